// Round 1
// 559.169 us; speedup vs baseline: 1.1885x; 1.1885x over previous
//
#include <hip/hip_runtime.h>
#include <hip/hip_bf16.h>
#include <hip/hip_fp16.h>

#define N_NODES 50000
#define N_EDGES 1600000
#define HIDDEN  128
#define EPS_C   0.3f
#define NWORDS  12500      // 50000 nodes, 4 u8 counters per u32 word
#define CHUNK   12500      // edges per histogram block; 128 chunks = 1.6M
#define NCHUNK  128

typedef _Float16 f16x8 __attribute__((ext_vector_type(8)));
typedef float    f32x16 __attribute__((ext_vector_type(16)));

// ---------------- per-chunk LDS histograms (u8-packed), zero global atomics ----------------
// grid 256: blocks 0..127 count rows (deg), 128..255 count cols (cnt)
__global__ __launch_bounds__(256) void k_hist(const int* __restrict__ ei, unsigned int* __restrict__ part) {
    __shared__ unsigned int hist[NWORDS];   // 50 KB
    int b = blockIdx.x;
    int type  = b >> 7;
    int chunk = b & 127;
    const int* src = ei + (size_t)type * N_EDGES + (size_t)chunk * CHUNK;
    for (int i = threadIdx.x; i < NWORDS; i += 256) hist[i] = 0;
    __syncthreads();
    for (int i = threadIdx.x; i < CHUNK; i += 256) {
        int v = src[i];
        atomicAdd(&hist[v >> 2], 1u << ((v & 3) * 8));
    }
    __syncthreads();
    unsigned int* dst = part + ((size_t)type * NCHUNK + chunk) * NWORDS;
    for (int i = threadIdx.x; i < NWORDS; i += 256) dst[i] = hist[i];
}

// ---------------- reduce partials -> nd, cnt, and per-(chunk,col) exclusive prefix ----------------
__global__ __launch_bounds__(256) void k_reduce(const unsigned int* __restrict__ part,
                                                float* __restrict__ nd, int* __restrict__ cnt,
                                                unsigned short* __restrict__ cntpre) {
    int w = blockIdx.x * 256 + threadIdx.x;
    if (w >= NWORDS) return;
    // deg (rows)
    unsigned int s0 = 0, s1 = 0, s2 = 0, s3 = 0;
    const unsigned int* dp = part + w;
    for (int b = 0; b < NCHUNK; ++b) {
        unsigned int v = dp[(size_t)b * NWORDS];
        s0 += v & 255u; s1 += (v >> 8) & 255u; s2 += (v >> 16) & 255u; s3 += v >> 24;
    }
    nd[4 * w + 0] = rsqrtf(fmaxf((float)s0, 1.f));
    nd[4 * w + 1] = rsqrtf(fmaxf((float)s1, 1.f));
    nd[4 * w + 2] = rsqrtf(fmaxf((float)s2, 1.f));
    nd[4 * w + 3] = rsqrtf(fmaxf((float)s3, 1.f));
    // cnt (cols) + exclusive prefix per chunk
    const unsigned int* cp = part + (size_t)NCHUNK * NWORDS + w;
    unsigned int r0 = 0, r1 = 0, r2 = 0, r3 = 0;
    for (int b = 0; b < NCHUNK; ++b) {
        size_t o = (size_t)b * N_NODES + 4 * w;
        *(ushort4*)&cntpre[o] = make_ushort4((unsigned short)r0, (unsigned short)r1,
                                             (unsigned short)r2, (unsigned short)r3);
        unsigned int v = cp[(size_t)b * NWORDS];
        r0 += v & 255u; r1 += (v >> 8) & 255u; r2 += (v >> 16) & 255u; r3 += v >> 24;
    }
    cnt[4 * w + 0] = (int)r0;
    cnt[4 * w + 1] = (int)r1;
    cnt[4 * w + 2] = (int)r2;
    cnt[4 * w + 3] = (int)r3;
}

// ---------------- 3-kernel exclusive scan of cnt -> colptr ----------------
__global__ __launch_bounds__(256) void k_scan_a(const int* __restrict__ cnt,
                                                int* __restrict__ out, int* __restrict__ partials) {
    __shared__ int sh[256];
    int t = threadIdx.x;
    int base = blockIdx.x * 1024 + t * 4;
    int v0 = (base + 0 < N_NODES) ? cnt[base + 0] : 0;
    int v1 = (base + 1 < N_NODES) ? cnt[base + 1] : 0;
    int v2 = (base + 2 < N_NODES) ? cnt[base + 2] : 0;
    int v3 = (base + 3 < N_NODES) ? cnt[base + 3] : 0;
    int s = v0 + v1 + v2 + v3;
    sh[t] = s;
    __syncthreads();
    for (int off = 1; off < 256; off <<= 1) {
        int add = (t >= off) ? sh[t - off] : 0;
        __syncthreads();
        sh[t] += add;
        __syncthreads();
    }
    int excl = sh[t] - s;
    if (t == 255) partials[blockIdx.x] = sh[255];
    if (base + 0 < N_NODES) out[base + 0] = excl;
    if (base + 1 < N_NODES) out[base + 1] = excl + v0;
    if (base + 2 < N_NODES) out[base + 2] = excl + v0 + v1;
    if (base + 3 < N_NODES) out[base + 3] = excl + v0 + v1 + v2;
}

__global__ void k_scan_b(int* partials, int* colptr, int nb) {
    if (threadIdx.x == 0 && blockIdx.x == 0) {
        int run = 0;
        for (int i = 0; i < nb; ++i) { int t = partials[i]; partials[i] = run; run += t; }
        colptr[N_NODES] = run;   // == E
    }
}

__global__ void k_scan_c(int* __restrict__ colptr, const int* __restrict__ partials) {
    int i = blockIdx.x * blockDim.x + threadIdx.x;
    if (i >= N_NODES) return;
    colptr[i] += partials[i >> 10];
}

// ---------------- scatter via LDS rank, zero global atomics ----------------
__global__ __launch_bounds__(256) void k_scatter2(const int* __restrict__ ei, const int* __restrict__ colptr,
                                                  const unsigned short* __restrict__ cntpre,
                                                  int* __restrict__ csr) {
    __shared__ unsigned int rank[NWORDS];   // 50 KB
    int b = blockIdx.x;
    for (int i = threadIdx.x; i < NWORDS; i += 256) rank[i] = 0;
    __syncthreads();
    const int* rs = ei + (size_t)b * CHUNK;
    const int* cs = ei + N_EDGES + (size_t)b * CHUNK;
    const unsigned short* pre = cntpre + (size_t)b * N_NODES;
    for (int i = threadIdx.x; i < CHUNK; i += 256) {
        int r = rs[i];
        int c = cs[i];
        unsigned int old = atomicAdd(&rank[c >> 2], 1u << ((c & 3) * 8));
        unsigned int lr = (old >> ((c & 3) * 8)) & 255u;
        int pos = colptr[c] + (int)pre[c] + (int)lr;
        csr[pos] = r;
    }
}

// ---------------- fp32 -> fp16 convert (n4 = count of float4) ----------------
__global__ void k_cvt(const float4* __restrict__ src, __half2* __restrict__ dst, int n4) {
    int i = blockIdx.x * 256 + threadIdx.x;
    if (i >= n4) return;
    float4 v = src[i];
    dst[2 * i]     = __floats2half2_rn(v.x, v.y);
    dst[2 * i + 1] = __floats2half2_rn(v.z, v.w);
}

// ---------------- GEMM1: h = relu(x @ W1^T + b1), fp16 MFMA, fused fp16 output ----------------
// block = 4 waves over M=64 x N=128; wave tile = M32 x N64 (two 32x32x16 accumulators)
__global__ __launch_bounds__(256) void k_gemm1(const float* __restrict__ x, const _Float16* __restrict__ wh,
                                               const float* __restrict__ bias, float* __restrict__ h,
                                               _Float16* __restrict__ hb) {
    int wave = threadIdx.x >> 6;
    int lane = threadIdx.x & 63;
    int mstrip = wave & 1;
    int nstrip = wave >> 1;
    int lm   = lane & 31;
    int half = lane >> 5;

    int m0 = blockIdx.x * 64 + mstrip * 32;
    int m  = m0 + lm;
    int mc = (m < N_NODES) ? m : (N_NODES - 1);   // clamp for loads; stores guarded
    int n0 = nstrip * 64;

    const float*    arow  = x  + (size_t)mc * 512 + half * 8;
    const _Float16* brow0 = wh + (size_t)(n0 + lm) * 512 + half * 8;
    const _Float16* brow1 = brow0 + (size_t)32 * 512;

    f32x16 acc0, acc1;
#pragma unroll
    for (int i = 0; i < 16; ++i) { acc0[i] = 0.f; acc1[i] = 0.f; }

#pragma unroll 4
    for (int k0 = 0; k0 < 512; k0 += 16) {
        float4 a0 = *(const float4*)(arow + k0);
        float4 a1 = *(const float4*)(arow + k0 + 4);
        f16x8 av;
        av[0] = (_Float16)a0.x; av[1] = (_Float16)a0.y; av[2] = (_Float16)a0.z; av[3] = (_Float16)a0.w;
        av[4] = (_Float16)a1.x; av[5] = (_Float16)a1.y; av[6] = (_Float16)a1.z; av[7] = (_Float16)a1.w;
        f16x8 b0 = *(const f16x8*)(brow0 + k0);
        f16x8 b1 = *(const f16x8*)(brow1 + k0);
        acc0 = __builtin_amdgcn_mfma_f32_32x32x16_f16(av, b0, acc0, 0, 0, 0);
        acc1 = __builtin_amdgcn_mfma_f32_32x32x16_f16(av, b1, acc1, 0, 0, 0);
    }

    // epilogue: C layout col=lane&31 (n), row=(reg&3)+8*(reg>>2)+4*half (m)
    float bs0 = bias[n0 + lm];
    float bs1 = bias[n0 + 32 + lm];
#pragma unroll
    for (int reg = 0; reg < 16; ++reg) {
        int row = (reg & 3) + 8 * (reg >> 2) + 4 * half;
        int gm = m0 + row;
        if (gm < N_NODES) {
            float v0 = fmaxf(acc0[reg] + bs0, 0.f);
            float v1 = fmaxf(acc1[reg] + bs1, 0.f);
            h[(size_t)gm * HIDDEN + n0 + lm]      = v0;
            h[(size_t)gm * HIDDEN + n0 + 32 + lm] = v1;
            hb[(size_t)gm * HIDDEN + n0 + lm]      = (_Float16)v0;
            hb[(size_t)gm * HIDDEN + n0 + 32 + lm] = (_Float16)v1;
        }
    }
}

// ---------------- per-node gate dots: dn = {h.w_r, nd}, dcb = h.w_c + gb ----------------
__global__ __launch_bounds__(256) void k_dot(const float* __restrict__ h, const float* __restrict__ gw,
                                             const float* __restrict__ gb, const float* __restrict__ nd,
                                             int layer, float2* __restrict__ dn, float* __restrict__ dcb) {
    int node = blockIdx.x * 4 + (threadIdx.x >> 6);
    int lane = threadIdx.x & 63;
    if (node >= N_NODES) return;
    const float2* hv = (const float2*)h;
    float2 wr = ((const float2*)(gw + layer * 256))[lane];
    float2 wc = ((const float2*)(gw + layer * 256 + 128))[lane];
    float2 hc = hv[(size_t)node * 64 + lane];
    float a = hc.x * wr.x + hc.y * wr.y;
    float b = hc.x * wc.x + hc.y * wc.y;
#pragma unroll
    for (int off = 32; off >= 1; off >>= 1) {
        a += __shfl_xor(a, off, 64);
        b += __shfl_xor(b, off, 64);
    }
    if (lane == 0) {
        dn[node]  = make_float2(a, nd[node]);
        dcb[node] = b + gb[layer];
    }
}

// ---------------- per-edge gate weight: warr[p] = tanh(dot_r[csr[p]] + dcb[col]) * nd[csr[p]] ----------------
// wave per node (col id is implicit => no colid array needed); lanes parallel over the segment
__global__ __launch_bounds__(256) void k_edgew(const int* __restrict__ csr, const int* __restrict__ colptr,
                                               const float2* __restrict__ dn, const float* __restrict__ dcb,
                                               float* __restrict__ warr) {
    int node = blockIdx.x * 4 + (threadIdx.x >> 6);
    int lane = threadIdx.x & 63;
    if (node >= N_NODES) return;
    float dc  = dcb[node];
    int beg = colptr[node], end = colptr[node + 1];
    for (int p = beg + lane; p < end; p += 64) {
        int r = csr[p];
        float2 v = dn[r];                      // {dot_r, nd[r]}  (400 KB table, L2-resident)
        float xx = v.x + dc;
        float t = __expf(2.0f * xx);           // saturates to inf / 0, no NaN below
        float g = 1.0f - 2.0f / (t + 1.0f);    // == tanh(xx)
        warr[p] = g * v.y;                     // nd[col] factored out, applied in k_prop epilogue
    }
}

// ---------------- propagation: wave per node, scalar-uniform edge stream, no shfl ----------------
__global__ __launch_bounds__(256) void k_prop(const __half2* __restrict__ hb, const float* __restrict__ raw,
                                              const int* __restrict__ colptr, const int* __restrict__ csr,
                                              const float* __restrict__ warr, const float* __restrict__ nd,
                                              float* __restrict__ hn, __half2* __restrict__ hbn) {
    int lane = threadIdx.x & 63;
    // force wave-uniform node/beg/end into SGPRs so csr[p]/warr[p] become s_loads
    int node = __builtin_amdgcn_readfirstlane(blockIdx.x * 4 + (threadIdx.x >> 6));
    int beg = __builtin_amdgcn_readfirstlane(colptr[node]);
    int end = __builtin_amdgcn_readfirstlane(colptr[node + 1]);
    float acc0 = 0.f, acc1 = 0.f;
    int p = beg;
    // 8 independent gathers in flight per wave; scalar loop control (no exec churn)
    for (; p + 8 <= end; p += 8) {
        int r0 = csr[p + 0], r1 = csr[p + 1], r2 = csr[p + 2], r3 = csr[p + 3];
        int r4 = csr[p + 4], r5 = csr[p + 5], r6 = csr[p + 6], r7 = csr[p + 7];
        float w0 = warr[p + 0], w1 = warr[p + 1], w2 = warr[p + 2], w3 = warr[p + 3];
        float w4 = warr[p + 4], w5 = warr[p + 5], w6 = warr[p + 6], w7 = warr[p + 7];
        __half2 v0 = hb[(size_t)r0 * 64 + lane];
        __half2 v1 = hb[(size_t)r1 * 64 + lane];
        __half2 v2 = hb[(size_t)r2 * 64 + lane];
        __half2 v3 = hb[(size_t)r3 * 64 + lane];
        __half2 v4 = hb[(size_t)r4 * 64 + lane];
        __half2 v5 = hb[(size_t)r5 * 64 + lane];
        __half2 v6 = hb[(size_t)r6 * 64 + lane];
        __half2 v7 = hb[(size_t)r7 * 64 + lane];
        acc0 = fmaf(w0, __low2float(v0), acc0);  acc1 = fmaf(w0, __high2float(v0), acc1);
        acc0 = fmaf(w1, __low2float(v1), acc0);  acc1 = fmaf(w1, __high2float(v1), acc1);
        acc0 = fmaf(w2, __low2float(v2), acc0);  acc1 = fmaf(w2, __high2float(v2), acc1);
        acc0 = fmaf(w3, __low2float(v3), acc0);  acc1 = fmaf(w3, __high2float(v3), acc1);
        acc0 = fmaf(w4, __low2float(v4), acc0);  acc1 = fmaf(w4, __high2float(v4), acc1);
        acc0 = fmaf(w5, __low2float(v5), acc0);  acc1 = fmaf(w5, __high2float(v5), acc1);
        acc0 = fmaf(w6, __low2float(v6), acc0);  acc1 = fmaf(w6, __high2float(v6), acc1);
        acc0 = fmaf(w7, __low2float(v7), acc0);  acc1 = fmaf(w7, __high2float(v7), acc1);
    }
    for (; p < end; ++p) {
        int r = csr[p];
        float w = warr[p];
        __half2 v = hb[(size_t)r * 64 + lane];
        acc0 = fmaf(w, __low2float(v), acc0);
        acc1 = fmaf(w, __high2float(v), acc1);
    }
    float ndc = nd[node];
    float2 rw = ((const float2*)raw)[(size_t)node * 64 + lane];
    float2 o;
    o.x = fmaf(EPS_C, rw.x, ndc * acc0);
    o.y = fmaf(EPS_C, rw.y, ndc * acc1);
    if (hn)  ((float2*)hn)[(size_t)node * 64 + lane] = o;
    if (hbn) hbn[(size_t)node * 64 + lane] = __floats2half2_rn(o.x, o.y);
}

// ---------------- output: logits = h @ W2^T + b2, then log_softmax ----------------
__global__ __launch_bounds__(256) void k_out(const float* __restrict__ h, const float* __restrict__ w2,
                                             const float* __restrict__ b2, float* __restrict__ out) {
    __shared__ float w2t[128][40];
    __shared__ float hs[4][128];
    int wid  = threadIdx.x >> 6;
    int lane = threadIdx.x & 63;
    int node = blockIdx.x * 4 + wid;

    for (int idx = threadIdx.x; idx < 40 * 128; idx += 256) {
        int j = idx >> 7;
        int i = idx & 127;
        w2t[i][j] = w2[idx];
    }
    if (node < N_NODES) {
        const float2* hvv = (const float2*)h;
        float2 v = hvv[(size_t)node * 64 + lane];
        hs[wid][2 * lane]     = v.x;
        hs[wid][2 * lane + 1] = v.y;
    }
    __syncthreads();
    if (node < N_NODES) {
        int j = lane;
        float logit = -INFINITY;
        if (j < 40) {
            float a = 0.f;
#pragma unroll 8
            for (int i = 0; i < 128; ++i) a = fmaf(hs[wid][i], w2t[i][j], a);
            logit = a + b2[j];
        }
        float mx = logit;
#pragma unroll
        for (int off = 32; off >= 1; off >>= 1) mx = fmaxf(mx, __shfl_xor(mx, off, 64));
        float ex = (j < 40) ? expf(logit - mx) : 0.f;
        float sum = ex;
#pragma unroll
        for (int off = 32; off >= 1; off >>= 1) sum += __shfl_xor(sum, off, 64);
        float ls = logf(sum);
        if (j < 40) out[(size_t)node * 40 + j] = logit - mx - ls;
    }
}

extern "C" void kernel_launch(void* const* d_in, const int* in_sizes, int n_in,
                              void* d_out, int out_size, void* d_ws, size_t ws_size,
                              hipStream_t stream) {
    const float* x   = (const float*)d_in[0];
    const int*   ei  = (const int*)  d_in[1];
    const float* t1w = (const float*)d_in[2];
    const float* t1b = (const float*)d_in[3];
    const float* gw  = (const float*)d_in[4];
    const float* gb  = (const float*)d_in[5];
    const float* w2  = (const float*)d_in[6];
    const float* b2  = (const float*)d_in[7];
    float* out = (float*)d_out;

    char* p = (char*)d_ws;
    int*    colptr   = (int*)p;    p += (size_t)(N_NODES + 64) * 4;
    int*    partials = (int*)p;    p += 256 * 4;
    float*  nd       = (float*)p;  p += (size_t)N_NODES * 4;
    int*    cnt      = (int*)p;    p += (size_t)N_NODES * 4;
    float*  dcb      = (float*)p;  p += (size_t)N_NODES * 4;
    float2* dn       = (float2*)p; p += (size_t)N_NODES * 8;
    int*    csr      = (int*)p;    p += (size_t)N_EDGES * 4;
    float*  warr     = (float*)p;  p += (size_t)N_EDGES * 4;        // per-edge gate weight
    _Float16* wh     = (_Float16*)p; p += (size_t)HIDDEN * 512 * 2;
    // transient region (dead after k_scatter2) overlaps the hb buffers (12.8+12.8 = 25.6 MB):
    char* q = p;
    unsigned int*   part   = (unsigned int*)q;                 // 2*128*12500*4 = 12.8 MB
    unsigned short* cntpre = (unsigned short*)(q + (size_t)2 * NCHUNK * NWORDS * 4);   // 12.8 MB
    // h region (written from k_gemm1 onward)
    __half2* hb0 = (__half2*)p; p += (size_t)N_NODES * 64 * 4;   // 12.8 MB
    __half2* hb1 = (__half2*)p; p += (size_t)N_NODES * 64 * 4;   // 12.8 MB
    float*  h0   = (float*)p;   p += (size_t)N_NODES * HIDDEN * 4;
    float*  h1   = (float*)p;   p += (size_t)N_NODES * HIDDEN * 4;
    float*  h2   = (float*)p;   p += (size_t)N_NODES * HIDDEN * 4;

    // ---- graph preprocessing (zero global atomics) ----
    k_hist<<<2 * NCHUNK, 256, 0, stream>>>(ei, part);
    k_reduce<<<(NWORDS + 255) / 256, 256, 0, stream>>>(part, nd, cnt, cntpre);
    int nb = (N_NODES + 1023) / 1024;   // 49
    k_scan_a<<<nb, 256, 0, stream>>>(cnt, colptr, partials);
    k_scan_b<<<1, 64, 0, stream>>>(partials, colptr, nb);
    k_scan_c<<<(N_NODES + 255) / 256, 256, 0, stream>>>(colptr, partials);
    k_scatter2<<<NCHUNK, 256, 0, stream>>>(ei, colptr, cntpre, csr);

    // ---- dense pipeline ----
    k_cvt<<<(16384 + 255) / 256, 256, 0, stream>>>((const float4*)t1w, (__half2*)wh, 16384);
    k_gemm1<<<(N_NODES + 63) / 64, 256, 0, stream>>>(x, wh, t1b, h0, (_Float16*)hb0);

    k_dot  <<<(N_NODES + 3) / 4, 256, 0, stream>>>(h0, gw, gb, nd, 0, dn, dcb);
    k_edgew<<<(N_NODES + 3) / 4, 256, 0, stream>>>(csr, colptr, dn, dcb, warr);
    k_prop <<<(N_NODES + 3) / 4, 256, 0, stream>>>(hb0, h0, colptr, csr, warr, nd, h1, hb1);

    k_dot  <<<(N_NODES + 3) / 4, 256, 0, stream>>>(h1, gw, gb, nd, 1, dn, dcb);
    k_edgew<<<(N_NODES + 3) / 4, 256, 0, stream>>>(csr, colptr, dn, dcb, warr);
    k_prop <<<(N_NODES + 3) / 4, 256, 0, stream>>>(hb1, h0, colptr, csr, warr, nd, h2, (__half2*)nullptr);

    k_out<<<(N_NODES + 3) / 4, 256, 0, stream>>>(h2, w2, b2, out);
}